// Round 1
// 152.370 us; speedup vs baseline: 1.0122x; 1.0122x over previous
//
#include <hip/hip_runtime.h>

// B=64, S=512, D=768 fp32.
// out = concat( hidden[:,0,:] (64*768), segment-mean by sent_id (64*20*768) )
// Grid (64 batches, 4 col-chunks of 192 floats) = 256 blocks = exactly 1/CU.
// Block (64 lanes, 16 waves) = 1024 threads.
// Each lane owns 3 columns at stride 64 -> three contiguous 256B/wave dword
// loads from one base reg (imm offsets 0/256/512). Counting-sort rows by sid
// once (int LDS atomics), then sorted segmented sum in registers (sid
// wave-uniform -> scalar branch), rare LDS flushes.
// 8-deep register prefetch ring = 6KB/wave, 96KB/CU in flight.

constexpr int B_ = 64;
constexpr int S_ = 512;
constexpr int D_ = 768;
constexpr int M1 = 21;    // sid in [0,20]
constexpr int MS = 20;    // segments emitted
constexpr int CF = 192;   // floats per column chunk (64 lanes x 3)
constexpr int NC = D_ / CF;  // 4 chunks -> 256 blocks
constexpr int G  = 16;    // waves per block
constexpr int RPW = S_ / G;  // 32 sorted positions per wave
constexpr int P  = 8;     // prefetch depth (rows)

__global__ __launch_bounds__(64 * G, 1)
void aspire_kernel(const float* __restrict__ hidden,
                   const int* __restrict__ sent_ids,
                   float* __restrict__ out) {
    __shared__ float acc[M1 * CF];    // 16128 B
    __shared__ int   cnt[M1];
    __shared__ int   offs[M1];
    __shared__ short ord[S_];         // row index, sorted by sid
    __shared__ short ssid[S_];        // sid at sorted position
    __shared__ int   sids[S_];

    const int b    = blockIdx.x;
    const int dc   = blockIdx.y;
    const int lane = threadIdx.x;     // 0..63
    const int g    = threadIdx.y;     // 0..15
    const int tid  = g * 64 + lane;

    // ---- init + counting sort (int atomics only; once per block) ----
    for (int i = tid; i < M1 * CF; i += 64 * G) acc[i] = 0.0f;
    if (tid < M1) cnt[tid] = 0;
    __syncthreads();
    if (tid < S_) {
        int sv = sent_ids[b * S_ + tid];
        sids[tid] = sv;
        atomicAdd(&cnt[sv], 1);       // ds_add_u32
    }
    __syncthreads();
    if (tid == 0) {
        int r = 0;
        for (int k = 0; k < M1; ++k) { offs[k] = r; r += cnt[k]; }
    }
    __syncthreads();
    if (tid < S_) {
        int sv  = sids[tid];
        int pos = atomicAdd(&offs[sv], 1);
        ord[pos]  = (short)tid;
        ssid[pos] = (short)sv;
    }
    // doc_cls_reps = hidden[:,0,:]
    if (tid < CF) {
        out[b * D_ + dc * CF + tid] = hidden[(size_t)b * S_ * D_ + dc * CF + tid];
    }
    __syncthreads();

    // ---- hot loop: sorted segmented sum, registers only ----
    // lane owns columns {dc*CF + lane, +64, +128}; each load is a contiguous
    // 256B wave transaction with immediate offset off one base pointer.
    const float* hb = hidden + (size_t)b * S_ * D_ + dc * CF + lane;
    const int p0 = g * RPW;

    float bx[P], by[P], bz[P];
    #pragma unroll
    for (int j = 0; j < P; ++j) {
        int s = ord[p0 + j];
        const float* p = hb + (size_t)s * D_;
        bx[j] = p[0]; by[j] = p[64]; bz[j] = p[128];
    }

    float s0 = 0.0f, s1 = 0.0f, s2 = 0.0f;
    int cur = ssid[p0];

    #pragma unroll 1
    for (int t0 = 0; t0 < RPW - P; t0 += P) {
        #pragma unroll
        for (int j = 0; j < P; ++j) {
            int t   = t0 + j;
            int sid = ssid[p0 + t];            // wave-uniform LDS read
            if (sid != cur) {                  // scalar branch, rare
                float* a = &acc[cur * CF + lane];
                atomicAdd(a,       s0);
                atomicAdd(a + 64,  s1);
                atomicAdd(a + 128, s2);
                s0 = s1 = s2 = 0.0f;
                cur = sid;
            }
            s0 += bx[j]; s1 += by[j]; s2 += bz[j];
            int sn = ord[p0 + t + P];          // refill (independent of adds)
            const float* p = hb + (size_t)sn * D_;
            bx[j] = p[0]; by[j] = p[64]; bz[j] = p[128];
        }
    }
    #pragma unroll
    for (int j = 0; j < P; ++j) {              // tail: consume only
        int t   = RPW - P + j;
        int sid = ssid[p0 + t];
        if (sid != cur) {
            float* a = &acc[cur * CF + lane];
            atomicAdd(a,       s0);
            atomicAdd(a + 64,  s1);
            atomicAdd(a + 128, s2);
            s0 = s1 = s2 = 0.0f;
            cur = sid;
        }
        s0 += bx[j]; s1 += by[j]; s2 += bz[j];
    }
    {   // final flush
        float* a = &acc[cur * CF + lane];
        atomicAdd(a,       s0);
        atomicAdd(a + 64,  s1);
        atomicAdd(a + 128, s2);
    }
    __syncthreads();

    // ---- epilogue: sent_reps = acc / max(cnt,1), coalesced ----
    float* srep = out + (size_t)B_ * D_;
    for (int f = tid; f < MS * CF; f += 64 * G) {
        int seg = f / CF;
        int col = f - seg * CF;
        float ct = (float)cnt[seg];
        ct = ct < 1.0f ? 1.0f : ct;
        srep[((size_t)b * MS + seg) * D_ + dc * CF + col] =
            acc[seg * CF + col] / ct;
    }
}

extern "C" void kernel_launch(void* const* d_in, const int* in_sizes, int n_in,
                              void* d_out, int out_size, void* d_ws, size_t ws_size,
                              hipStream_t stream) {
    const float* hidden   = (const float*)d_in[0];
    const int*   sent_ids = (const int*)d_in[1];
    float* out = (float*)d_out;

    dim3 grid(B_, NC);        // (64, 4) = 256 blocks = 1 per CU
    dim3 block(64, G);        // 1024 threads = 16 waves
    aspire_kernel<<<grid, block, 0, stream>>>(hidden, sent_ids, out);
}